// Round 4
// baseline (148.417 us; speedup 1.0000x reference)
//
#include <hip/hip_runtime.h>
#include <hip/hip_fp16.h>

// L=8 layers, H=512, K=16 links, N_IN=512, B=8192; out = last 512 cols (fp32).
#define LAYERS 8
#define H      512
#define K      16
#define N_IN   512
#define BATCH  8192
#define R      8      // batch rows per block; 8 x f16 = 16 B -> one ds_read_b128 per gather
#define NT     1024   // 16 waves/block; 64 KB LDS -> 2 blocks/CU -> 32 waves/CU (100%)
// Layer l gathers from cols [0, 512+512*l); max l=7 -> cols < 4096. Layer 7's
// output is never gathered -> straight to global. LDS = 4096*16 B = 64 KB.
#define LDS_COLS 4096

// Pure-VALU pair exchange: quad_perm(1,0,3,2) = lane ^ 1. Avoids __shfl_xor,
// which lowers through the LDS pipe.
__device__ __forceinline__ float dpp_xor1(float x) {
    return __int_as_float(__builtin_amdgcn_update_dpp(
        0, __float_as_int(x), 0xB1, 0xF, 0xF, true));
}

// NOTE: __launch_bounds__ 2nd arg behaves like CUDA min-blocks-per-CU here:
// (1024, 8) produced VGPR_Count=32 -> ~25 spilled regs/thread -> 115 MB of
// scratch WRITE traffic (R3). (1024, 2) = 2 blocks/CU * 16 waves = 32 waves/CU
// -> VGPR cap 64, which fits this kernel's ~50-reg working set.
__global__ __launch_bounds__(NT, 2)
void ffn_fused_kernel(const float* __restrict__ x,
                      const int*   __restrict__ link_idx,
                      const float* __restrict__ weights,
                      const float* __restrict__ bias,
                      float*       __restrict__ out)
{
    // vals[c*R + r] = f16 value of column c, block batch-row r.
    __shared__ __align__(16) __half vals[LDS_COLS * R];   // 65536 B

    const int tid  = threadIdx.x;
    const int h    = tid >> 1;   // lane pair (2i,2i+1) shares output unit h
    const int half = tid & 1;    // which 8 of the 16 links / which 4 of 8 rows
    const int row0 = blockIdx.x * R;

    // ---- Stage x into LDS as f16: thread handles col h, rows half*4..+3 ----
    {
        float v[4];
        #pragma unroll
        for (int j = 0; j < 4; ++j)
            v[j] = x[(row0 + half * 4 + j) * N_IN + h];
        __half2 p[2];
        p[0] = __floats2half2_rn(v[0], v[1]);
        p[1] = __floats2half2_rn(v[2], v[3]);
        *(uint2*)&vals[h * R + half * 4] = *(const uint2*)p;   // 8 B, lane-consecutive
    }
    __syncthreads();

    // ---- Layers ----
    for (int l = 0; l < LAYERS; ++l) {
        const int base = (l * H + h) * K + half * 8;
        int   idx[8];
        float w[8];
        *(int4*)  &idx[0] = ((const int4*)  (link_idx + base))[0];  // pair-coalesced 64 B
        *(int4*)  &idx[4] = ((const int4*)  (link_idx + base))[1];
        *(float4*)&w[0]   = ((const float4*)(weights  + base))[0];
        *(float4*)&w[4]   = ((const float4*)(weights  + base))[1];

        const float b = half ? 0.0f : bias[l * H + h];  // bias added once per pair
        float acc[R];
        #pragma unroll
        for (int r = 0; r < R; ++r) acc[r] = b;

        #pragma unroll
        for (int k = 0; k < 8; ++k) {
            // one ds_read_b128 = 8 rows of column idx[k]
            const uint4 g = *(const uint4*)&vals[idx[k] * R];
            const __half2* hp = (const __half2*)&g;
            const float wk = w[k];
            #pragma unroll
            for (int r = 0; r < R / 2; ++r) {
                const float2 f = __half22float2(hp[r]);   // folds into v_fma_mix_f32
                acc[2 * r]     = fmaf(f.x, wk, acc[2 * r]);
                acc[2 * r + 1] = fmaf(f.y, wk, acc[2 * r + 1]);
            }
        }

        // pair-reduce all 8 rows (uniform register indices; DPP is wave-wide)
        float t[R];
        #pragma unroll
        for (int r = 0; r < R; ++r)
            t[r] = acc[r] + dpp_xor1(acc[r]);

        // each lane finishes its 4 rows: half==0 -> rows 0..3, half==1 -> rows 4..7
        float o[4];
        #pragma unroll
        for (int j = 0; j < 4; ++j) {
            const float s = half ? t[4 + j] : t[j];       // v_cndmask, const reg idx
            o[j] = 1.0f / (1.0f + __expf(-s));
        }

        if (l < LAYERS - 1) {
            __half2 p[2];
            p[0] = __floats2half2_rn(o[0], o[1]);
            p[1] = __floats2half2_rn(o[2], o[3]);
            *(uint2*)&vals[(N_IN + l * H + h) * R + half * 4] = *(const uint2*)p;
            __syncthreads();
        } else {
            #pragma unroll
            for (int j = 0; j < 4; ++j)
                out[(row0 + half * 4 + j) * H + h] = o[j];
        }
    }
}

extern "C" void kernel_launch(void* const* d_in, const int* in_sizes, int n_in,
                              void* d_out, int out_size, void* d_ws, size_t ws_size,
                              hipStream_t stream) {
    const float* x        = (const float*)d_in[0];
    const int*   link_idx = (const int*)  d_in[1];
    const float* weights  = (const float*)d_in[2];
    const float* bias     = (const float*)d_in[3];
    float*       out      = (float*)d_out;

    ffn_fused_kernel<<<dim3(BATCH / R), dim3(NT), 0, stream>>>(x, link_idx, weights, bias, out);
}

// Round 5
// 109.401 us; speedup vs baseline: 1.3566x; 1.3566x over previous
//
#include <hip/hip_runtime.h>
#include <hip/hip_fp16.h>

// L=8 layers, H=512, K=16 links, N_IN=512, B=8192; out = last 512 cols (fp32).
#define LAYERS 8
#define H      512
#define K      16
#define N_IN   512
#define BATCH  8192
#define R      8      // batch rows per block; 8 x f16 = 16 B -> one ds_read_b128 per gather
#define NT     512    // 8 waves/block; 64 KB LDS -> 2 blocks/CU -> 16 waves/CU
// Layer l gathers from cols [0, 512+512*l); max l=7 -> cols < 4096. Layer 7's
// output is never gathered -> straight to global. LDS = 4096*16 B = 64 KB.
#define LDS_COLS 4096

// NOTE (R3/R4): NT=1024 variants spill regardless of __launch_bounds__ (VGPR
// forced to 32/36, ~30 MB scratch writes). Staying at NT=512 where the
// allocator behaves (R2: 52 VGPR, clean).

__global__ __launch_bounds__(NT, 2)
void ffn_fused_kernel(const float* __restrict__ x,
                      const int*   __restrict__ link_idx,
                      const float* __restrict__ weights,
                      const float* __restrict__ bias,
                      float*       __restrict__ out)
{
    // vals[c*R + r] = f16 value of column c, block batch-row r.
    __shared__ __align__(16) __half vals[LDS_COLS * R];   // 65536 B

    const int tid  = threadIdx.x;
    const int row0 = blockIdx.x * R;

    // ---- Stage x rows into LDS as f16 (each thread owns one column) ----
    {
        const int c = tid;                     // NT == N_IN == 512
        float v[R];
        #pragma unroll
        for (int r = 0; r < R; ++r)
            v[r] = x[(row0 + r) * N_IN + c];   // coalesced per r
        __half2 p[R / 2];
        #pragma unroll
        for (int r = 0; r < R / 2; ++r)
            p[r] = __floats2half2_rn(v[2 * r], v[2 * r + 1]);
        *(uint4*)&vals[c * R] = *(const uint4*)p;   // one ds_write_b128
    }

    // ---- Preload layer-0 params while LDS staging drains (before barrier) ----
    int   idxA[K]; float wA[K]; float bA;
    {
        const int base = tid * K;              // l=0, h=tid
        #pragma unroll
        for (int q = 0; q < 4; ++q) {
            *(int4*)  &idxA[4 * q] = ((const int4*)  (link_idx + base))[q];
            *(float4*)&wA  [4 * q] = ((const float4*)(weights  + base))[q];
        }
        bA = bias[tid];
    }

    __syncthreads();

    // ---- Layers (each thread owns one h; 8 batch rows in registers) ----
    #pragma unroll
    for (int l = 0; l < LAYERS; ++l) {
        // Prefetch next layer's params under this layer's gather/FMA work,
        // instead of stalling on L2 right after the barrier.
        int idxB[K]; float wB[K]; float bB = 0.0f;
        if (l < LAYERS - 1) {
            const int nb = ((l + 1) * H + tid) * K;
            #pragma unroll
            for (int q = 0; q < 4; ++q) {
                *(int4*)  &idxB[4 * q] = ((const int4*)  (link_idx + nb))[q];
                *(float4*)&wB  [4 * q] = ((const float4*)(weights  + nb))[q];
            }
            bB = bias[(l + 1) * H + tid];
        }

        float acc[R];
        #pragma unroll
        for (int r = 0; r < R; ++r) acc[r] = bA;

        #pragma unroll
        for (int k = 0; k < K; ++k) {
            // one ds_read_b128 = 8 rows of column idxA[k]
            const uint4 g = *(const uint4*)&vals[idxA[k] * R];
            const __half2* hp = (const __half2*)&g;
            const float wk = wA[k];
            #pragma unroll
            for (int r = 0; r < R / 2; ++r) {
                const float2 f = __half22float2(hp[r]);   // folds into v_fma_mix_f32
                acc[2 * r]     = fmaf(f.x, wk, acc[2 * r]);
                acc[2 * r + 1] = fmaf(f.y, wk, acc[2 * r + 1]);
            }
        }

        // sigmoid via v_rcp_f32 (~1 ulp) instead of the ~10-instr exact divide
        #pragma unroll
        for (int r = 0; r < R; ++r)
            acc[r] = __builtin_amdgcn_rcpf(1.0f + __expf(-acc[r]));

        if (l < LAYERS - 1) {
            __half2 p[R / 2];
            #pragma unroll
            for (int r = 0; r < R / 2; ++r)
                p[r] = __floats2half2_rn(acc[2 * r], acc[2 * r + 1]);
            *(uint4*)&vals[(N_IN + l * H + tid) * R] = *(const uint4*)p;
            __syncthreads();
            // rotate prefetched params in (full unroll -> register renaming, no moves)
            #pragma unroll
            for (int k = 0; k < K; ++k) { idxA[k] = idxB[k]; wA[k] = wB[k]; }
            bA = bB;
        } else {
            // final layer: coalesced fp32 stores (lanes -> consecutive h)
            #pragma unroll
            for (int r = 0; r < R; ++r)
                out[(row0 + r) * H + tid] = acc[r];
        }
    }
}

extern "C" void kernel_launch(void* const* d_in, const int* in_sizes, int n_in,
                              void* d_out, int out_size, void* d_ws, size_t ws_size,
                              hipStream_t stream) {
    const float* x        = (const float*)d_in[0];
    const int*   link_idx = (const int*)  d_in[1];
    const float* weights  = (const float*)d_in[2];
    const float* bias     = (const float*)d_in[3];
    float*       out      = (float*)d_out;

    ffn_fused_kernel<<<dim3(BATCH / R), dim3(NT), 0, stream>>>(x, link_idx, weights, bias, out);
}